// Round 2
// baseline (666.286 us; speedup 1.0000x reference)
//
#include <hip/hip_runtime.h>
#include <hip/hip_bf16.h>
#include <stdint.h>

#define NCLS 36
#define HDIM 256
#define BSZ  32
#define LLOC 196
#define DIN  1024
#define NCH  (NCLS * HDIM)   // 9216

__device__ __forceinline__ void dot8f(float& acc, const float* __restrict__ w,
                                      const float* __restrict__ x) {
  float4 w0 = *(const float4*)w;
  float4 w1 = *(const float4*)(w + 4);
  acc += w0.x * x[0] + w0.y * x[1] + w0.z * x[2] + w0.w * x[3]
       + w1.x * x[4] + w1.y * x[5] + w1.z * x[6] + w1.w * x[7];
}

// ---- kernel 0: gap [32,1024] f32 -> gap_t [1024][32] f32 --------------------
__global__ void k0_gap_t(const float* __restrict__ gap, float* __restrict__ gap_t) {
  int i = blockIdx.x * 256 + threadIdx.x;          // 32768 exact
  int b = i >> 10, k = i & 1023;
  gap_t[k * BSZ + b] = gap[i];
}

// ---- kernel 1: xg[b, n] = gap[b,:] @ Wg[:, n] + bg[n]  (n = c*256+h) --------
// block = 512 threads: 64 columns x 8 groups of 4 batches. grid = 9216/64 = 144
__global__ __launch_bounds__(512) void k1_xg(
    const float* __restrict__ Wg, const float* __restrict__ bg,
    const float* __restrict__ gap_t, float* __restrict__ xg) {
  int lane = threadIdx.x & 63;
  int g8   = threadIdx.x >> 6;          // 0..7
  int n    = blockIdx.x * 64 + lane;
  int b0   = g8 * 4;
  float bias = bg[n];
  float a0 = 0.f, a1 = 0.f, a2 = 0.f, a3 = 0.f;
  const float* wp = Wg + n;
  const float* gp = gap_t + b0;
  #pragma unroll 4
  for (int k = 0; k < DIN; ++k) {
    float w = wp[(size_t)k * NCH];
    float4 g = *(const float4*)(gp + k * BSZ);
    a0 += g.x * w; a1 += g.y * w; a2 += g.z * w; a3 += g.w * w;
  }
  xg[(size_t)(b0 + 0) * NCH + n] = a0 + bias;
  xg[(size_t)(b0 + 1) * NCH + n] = a1 + bias;
  xg[(size_t)(b0 + 2) * NCH + n] = a2 + bias;
  xg[(size_t)(b0 + 3) * NCH + n] = a3 + bias;
}

// ---- kernel 2: fused per-(b,c) attention + heads ----------------------------
// grid = (32, 36): b = blockIdx.x (fast -> consecutive blocks share Wl_c in L2)
__global__ __launch_bounds__(256) void k2_main(
    const float* __restrict__ local,   // [32,196,1024]
    const float* __restrict__ Wl,      // [1024, 9216]
    const float* __restrict__ bl,      // [9216]
    const float* __restrict__ Wh,      // [256,256]
    const float* __restrict__ bh,      // [256]
    const float* __restrict__ Wr,      // [256,4]
    const float* __restrict__ br,      // [4]
    const float* __restrict__ Wc,      // [256]
    const float* __restrict__ bc,      // [1]
    const float* __restrict__ xg,      // [32, 9216] f32
    float* __restrict__ out)           // [4608 coords | 1152 presence] f32
{
  __shared__ float xg_s[HDIM];
  __shared__ float v_s[DIN];
  __shared__ float sc_s[256];
  __shared__ float attn_s[256];
  __shared__ float u_s[DIN];
  __shared__ float ws_s[HDIM];
  __shared__ float hid_s[HDIM];

  const int tid = threadIdx.x;
  const int b = blockIdx.x;
  const int c = blockIdx.y;

  xg_s[tid] = xg[(size_t)b * NCH + c * HDIM + tid];
  __syncthreads();

  // ---- step a: v[k] = Wl[k, c*256 : +256] . xg   (4 rows per thread) ----
  {
    const float* r0 = Wl + (size_t)tid * NCH + c * HDIM;
    const float* r1 = r0 + (size_t)256 * NCH;
    const float* r2 = r1 + (size_t)256 * NCH;
    const float* r3 = r2 + (size_t)256 * NCH;
    float a0 = 0.f, a1 = 0.f, a2 = 0.f, a3 = 0.f;
    #pragma unroll 2
    for (int j = 0; j < 32; ++j) {
      float x[8];
      *(float4*)&x[0] = *(const float4*)&xg_s[j * 8];
      *(float4*)&x[4] = *(const float4*)&xg_s[j * 8 + 4];
      dot8f(a0, r0 + j * 8, x);
      dot8f(a1, r1 + j * 8, x);
      dot8f(a2, r2 + j * 8, x);
      dot8f(a3, r3 + j * 8, x);
    }
    v_s[tid]       = a0;
    v_s[tid + 256] = a1;
    v_s[tid + 512] = a2;
    v_s[tid + 768] = a3;
  }
  __syncthreads();

  // ---- step b: dot[l] = local[b,l,:] . v  (one l per thread, 196 active) ----
  if (tid < LLOC) {
    const float* lp = local + ((size_t)b * LLOC + tid) * DIN;
    float acc = 0.f;
    #pragma unroll 2
    for (int j = 0; j < 128; ++j) {
      float x[8];
      *(float4*)&x[0] = *(const float4*)&v_s[j * 8];
      *(float4*)&x[4] = *(const float4*)&v_s[j * 8 + 4];
      dot8f(acc, lp + j * 8, x);
    }
    sc_s[tid] = acc;
  }
  __syncthreads();

  // ---- step c: softmax over l (wave 0) ----
  if (tid < 64) {
    float m = -1e30f;
    for (int l = tid; l < LLOC; l += 64) m = fmaxf(m, sc_s[l]);
    #pragma unroll
    for (int off = 32; off >= 1; off >>= 1) m = fmaxf(m, __shfl_xor(m, off));
    float s = 0.f;
    for (int l = tid; l < LLOC; l += 64) {
      float e = __expf(sc_s[l] - m);
      attn_s[l] = e; s += e;
    }
    #pragma unroll
    for (int off = 32; off >= 1; off >>= 1) s += __shfl_xor(s, off);
    float inv = 1.0f / s;
    for (int l = tid; l < LLOC; l += 64) attn_s[l] *= inv;
  }
  __syncthreads();

  // ---- step d: u[k] = sum_l attn[l] * local[b,l,k]  (4 k per thread) ----
  {
    const float* lp = local + (size_t)b * LLOC * DIN + tid * 4;
    float a0 = 0.f, a1 = 0.f, a2 = 0.f, a3 = 0.f;
    #pragma unroll 4
    for (int l = 0; l < LLOC; ++l) {
      float w = attn_s[l];
      float4 q = *(const float4*)(lp + (size_t)l * DIN);
      a0 += w * q.x; a1 += w * q.y; a2 += w * q.z; a3 += w * q.w;
    }
    *(float4*)&u_s[tid * 4] = make_float4(a0, a1, a2, a3);
  }
  __syncthreads();

  // ---- step e: ws[h] = u . Wl[:, c*256+h] + bl[c*256+h]  (h = tid) ----
  {
    float acc = bl[c * HDIM + tid];
    const float* wp = Wl + c * HDIM + tid;
    for (int k = 0; k < DIN; k += 4) {
      float4 uu = *(const float4*)&u_s[k];
      acc += uu.x * wp[(size_t)(k + 0) * NCH];
      acc += uu.y * wp[(size_t)(k + 1) * NCH];
      acc += uu.z * wp[(size_t)(k + 2) * NCH];
      acc += uu.w * wp[(size_t)(k + 3) * NCH];
    }
    ws_s[tid] = acc;
  }
  __syncthreads();

  // ---- step f: hid[j] = relu(ws . Wh[:, j] + bh[j])  (j = tid) ----
  {
    float acc = bh[tid];
    const float* wp = Wh + tid;
    for (int h = 0; h < HDIM; h += 4) {
      float4 ww = *(const float4*)&ws_s[h];
      acc += ww.x * wp[(h + 0) * HDIM];
      acc += ww.y * wp[(h + 1) * HDIM];
      acc += ww.z * wp[(h + 2) * HDIM];
      acc += ww.w * wp[(h + 3) * HDIM];
    }
    hid_s[tid] = fmaxf(acc, 0.0f);
  }
  __syncthreads();

  // ---- step g: outputs. wave w computes coord r=w; wave 0 also presence ----
  {
    int w = tid >> 6, j0 = tid & 63;
    float acc = 0.f;
    #pragma unroll
    for (int m2 = 0; m2 < 4; ++m2) {
      int j = j0 + 64 * m2;
      acc += hid_s[j] * Wr[j * 4 + w];
    }
    #pragma unroll
    for (int off = 32; off >= 1; off >>= 1) acc += __shfl_xor(acc, off);
    if (j0 == 0)
      out[(size_t)b * (NCLS * 4) + c * 4 + w] = acc + br[w];

    if (w == 0) {
      float p = 0.f;
      #pragma unroll
      for (int m2 = 0; m2 < 4; ++m2) {
        int j = j0 + 64 * m2;
        p += hid_s[j] * Wc[j];
      }
      #pragma unroll
      for (int off = 32; off >= 1; off >>= 1) p += __shfl_xor(p, off);
      if (j0 == 0)
        out[BSZ * NCLS * 4 + b * NCLS + c] = p + bc[0];
    }
  }
}

extern "C" void kernel_launch(void* const* d_in, const int* in_sizes, int n_in,
                              void* d_out, int out_size, void* d_ws, size_t ws_size,
                              hipStream_t stream) {
  const float* local = (const float*)d_in[0];
  const float* gap   = (const float*)d_in[1];
  const float* Wl    = (const float*)d_in[2];
  const float* bl    = (const float*)d_in[3];
  const float* Wg    = (const float*)d_in[4];
  const float* bg    = (const float*)d_in[5];
  const float* Wh    = (const float*)d_in[6];
  const float* bh    = (const float*)d_in[7];
  const float* Wr    = (const float*)d_in[8];
  const float* br    = (const float*)d_in[9];
  const float* Wc    = (const float*)d_in[10];
  const float* bc    = (const float*)d_in[11];
  float* out         = (float*)d_out;

  float* gap_t = (float*)d_ws;                 // [1024][32] f32 = 128 KB
  float* xg    = gap_t + (size_t)BSZ * DIN;    // [32][9216]  f32 = 1.18 MB

  k0_gap_t<<<dim3(BSZ * DIN / 256), dim3(256), 0, stream>>>(gap, gap_t);
  k1_xg<<<dim3(NCH / 64), dim3(512), 0, stream>>>(Wg, bg, gap_t, xg);
  k2_main<<<dim3(BSZ, NCLS), dim3(256), 0, stream>>>(
      local, Wl, bl, Wh, bh, Wr, br, Wc, bc, xg, out);
}

// Round 3
// 330.739 us; speedup vs baseline: 2.0145x; 2.0145x over previous
//
#include <hip/hip_runtime.h>
#include <hip/hip_bf16.h>
#include <stdint.h>

#define NCLS 36
#define HDIM 256
#define BSZ  32
#define LLOC 196
#define DIN  1024
#define NCH  9216          // NCLS*HDIM

#define XG_N 294912        // BSZ*NCH
#define SC_N 225792        // BSZ*NCLS*LLOC
#define V_N  1179648       // BSZ*NCLS*DIN

// ---------------------------------------------------------------------------
// kB: xg partials. xg_part[ks][b][n] = sum_{k in ks-chunk} gap[b][k]*Wg[k][n]
// grid (72 ntile128, 4 ksplit) x 256. wave w owns b-octet w*8 (uniform -> s_load gap).
__global__ __launch_bounds__(256) void kB_xg_part(
    const float* __restrict__ Wg, const float* __restrict__ gap,
    float* __restrict__ xg_part) {
  const int nt = blockIdx.x;
  const int ks = blockIdx.y;
  const int t  = threadIdx.x;
  const int b0 = __builtin_amdgcn_readfirstlane(t >> 6) * 8;
  const int n  = nt * 128 + (t & 63);
  const int kbase = ks * 256;
  float acc0[8] = {0,0,0,0,0,0,0,0};
  float acc1[8] = {0,0,0,0,0,0,0,0};
  for (int k4 = 0; k4 < 64; ++k4) {
    const int k = kbase + k4 * 4;
    float4 g[8];
    #pragma unroll
    for (int bi = 0; bi < 8; ++bi)
      g[bi] = *(const float4*)&gap[(size_t)(b0 + bi) * DIN + k];
    #pragma unroll
    for (int m = 0; m < 4; ++m) {
      const float* wr = Wg + (size_t)(k + m) * NCH + n;
      float w0 = wr[0], w1 = wr[64];
      #pragma unroll
      for (int bi = 0; bi < 8; ++bi) {
        float gv = (&g[bi].x)[m];
        acc0[bi] += w0 * gv;
        acc1[bi] += w1 * gv;
      }
    }
  }
  #pragma unroll
  for (int bi = 0; bi < 8; ++bi) {
    size_t o = (size_t)(ks * BSZ + b0 + bi) * NCH + n;
    xg_part[o]      = acc0[bi];
    xg_part[o + 64] = acc1[bi];
  }
}

// kBr: xg = bg + sum of 4 partials. grid 1152 x 256.
__global__ void kBr_xg(const float* __restrict__ xg_part,
                       const float* __restrict__ bg, float* __restrict__ xg) {
  int i = blockIdx.x * 256 + threadIdx.x;
  float s = bg[i % NCH];
  s += xg_part[i] + xg_part[XG_N + i] + xg_part[2 * XG_N + i] + xg_part[3 * XG_N + i];
  xg[i] = s;
}

// ---------------------------------------------------------------------------
// kC: V[b][c][k] = sum_h Wl[k][c*256+h] * xg[b][c*256+h]
// grid (36 c, 8 kchunk128) x 256. wave w owns b-octet w*8; lanes = 64 k.
__global__ __launch_bounds__(256) void kC_V(
    const float* __restrict__ Wl, const float* __restrict__ xg,
    float* __restrict__ V) {
  const int c  = blockIdx.x;
  const int kc = blockIdx.y;
  const int t  = threadIdx.x;
  const int b0 = __builtin_amdgcn_readfirstlane(t >> 6) * 8;
  const int k  = kc * 128 + (t & 63);
  float acc0[8] = {0,0,0,0,0,0,0,0};
  float acc1[8] = {0,0,0,0,0,0,0,0};
  const float* wl0 = Wl + (size_t)k * NCH + c * HDIM;
  const float* wl1 = wl0 + (size_t)64 * NCH;
  const float* xgb = xg + c * HDIM;
  for (int j = 0; j < 64; ++j) {
    float4 w0 = *(const float4*)&wl0[j * 4];
    float4 w1 = *(const float4*)&wl1[j * 4];
    #pragma unroll
    for (int bi = 0; bi < 8; ++bi) {
      float4 x = *(const float4*)&xgb[(size_t)(b0 + bi) * NCH + j * 4];
      acc0[bi] += w0.x * x.x + w0.y * x.y + w0.z * x.z + w0.w * x.w;
      acc1[bi] += w1.x * x.x + w1.y * x.y + w1.z * x.z + w1.w * x.w;
    }
  }
  #pragma unroll
  for (int bi = 0; bi < 8; ++bi) {
    size_t o = (size_t)((b0 + bi) * NCLS + c) * DIN + k;
    V[o]      = acc0[bi];
    V[o + 64] = acc1[bi];
  }
}

// ---------------------------------------------------------------------------
// kD: score partials. scores_part[ks][b][c][l] = sum_{k chunk} local[b][l][k]*V[b][c][k]
// grid (32 b, 3 cg12, 4 ksplit) x 256 (196 active, thread = l). V reads are uniform -> s_load.
__global__ __launch_bounds__(256) void kD_scores(
    const float* __restrict__ local, const float* __restrict__ V,
    float* __restrict__ scores_part) {
  const int b  = blockIdx.x;
  const int cg = blockIdx.y;
  const int ks = blockIdx.z;
  const int l  = threadIdx.x;
  if (l >= LLOC) return;
  const float* lp = local + (size_t)(b * LLOC + l) * DIN + ks * 256;
  const float* vp = V + (size_t)(b * NCLS + cg * 12) * DIN + ks * 256;
  float acc[12] = {0,0,0,0,0,0,0,0,0,0,0,0};
  for (int j = 0; j < 64; ++j) {
    float4 a = *(const float4*)&lp[j * 4];
    #pragma unroll
    for (int ci = 0; ci < 12; ++ci) {
      float4 v = *(const float4*)&vp[(size_t)ci * DIN + j * 4];
      acc[ci] += a.x * v.x + a.y * v.y + a.z * v.z + a.w * v.w;
    }
  }
  #pragma unroll
  for (int ci = 0; ci < 12; ++ci)
    scores_part[(size_t)ks * SC_N + (size_t)(b * NCLS + cg * 12 + ci) * LLOC + l] = acc[ci];
}

// ---------------------------------------------------------------------------
// kE: reduce 4 partials + softmax over l; write attn transposed [b][l][36].
// grid (32, 36) x 64.
__global__ __launch_bounds__(64) void kE_softmax(
    const float* __restrict__ scores_part, float* __restrict__ attn_t) {
  const int b = blockIdx.x, c = blockIdx.y, t = threadIdx.x;
  const size_t base = (size_t)(b * NCLS + c) * LLOC;
  float sc[4];
  int nl = 0;
  float m = -1e30f;
  for (int l = t; l < LLOC; l += 64) {
    float s = scores_part[base + l] + scores_part[SC_N + base + l]
            + scores_part[2 * SC_N + base + l] + scores_part[3 * SC_N + base + l];
    sc[nl++] = s; m = fmaxf(m, s);
  }
  #pragma unroll
  for (int off = 32; off >= 1; off >>= 1) m = fmaxf(m, __shfl_xor(m, off));
  float sum = 0.f;
  for (int i = 0; i < nl; ++i) { sc[i] = __expf(sc[i] - m); sum += sc[i]; }
  #pragma unroll
  for (int off = 32; off >= 1; off >>= 1) sum += __shfl_xor(sum, off);
  float inv = 1.0f / sum;
  nl = 0;
  for (int l = t; l < LLOC; l += 64)
    attn_t[(size_t)(b * LLOC + l) * NCLS + c] = sc[nl++] * inv;
}

// ---------------------------------------------------------------------------
// kF: U[b][c][k] = sum_l attn[b][c][l] * local[b][l][k]
// grid (32 b, 4 kchunk256, 3 cg12) x 256 (thread = k). attn reads uniform -> s_load.
__global__ __launch_bounds__(256) void kF_U(
    const float* __restrict__ local, const float* __restrict__ attn_t,
    float* __restrict__ U) {
  const int b = blockIdx.x, ks = blockIdx.y, cg = blockIdx.z;
  const int k = ks * 256 + threadIdx.x;
  float acc[12] = {0,0,0,0,0,0,0,0,0,0,0,0};
  const float* lp = local + (size_t)b * LLOC * DIN + k;
  const float* ap = attn_t + (size_t)b * LLOC * NCLS + cg * 12;
  for (int l = 0; l < LLOC; ++l) {
    float a = lp[(size_t)l * DIN];
    float4 w0 = *(const float4*)&ap[l * NCLS + 0];
    float4 w1 = *(const float4*)&ap[l * NCLS + 4];
    float4 w2 = *(const float4*)&ap[l * NCLS + 8];
    acc[0] += a * w0.x;  acc[1] += a * w0.y;  acc[2]  += a * w0.z;  acc[3]  += a * w0.w;
    acc[4] += a * w1.x;  acc[5] += a * w1.y;  acc[6]  += a * w1.z;  acc[7]  += a * w1.w;
    acc[8] += a * w2.x;  acc[9] += a * w2.y;  acc[10] += a * w2.z;  acc[11] += a * w2.w;
  }
  #pragma unroll
  for (int ci = 0; ci < 12; ++ci)
    U[(size_t)(b * NCLS + cg * 12 + ci) * DIN + k] = acc[ci];
}

// ---------------------------------------------------------------------------
// kG: wsh[b][c][h] = bl[c*256+h] + sum_k U[b][c][k] * Wl[k][c*256+h]
// grid (36 c, 4 htile64, 2 bhalf16) x 256. wave w owns b-quad (uniform U -> s_load).
__global__ __launch_bounds__(256) void kG_ws(
    const float* __restrict__ Wl, const float* __restrict__ U,
    const float* __restrict__ bl, float* __restrict__ wsh) {
  const int c = blockIdx.x, ht = blockIdx.y, bh = blockIdx.z;
  const int t = threadIdx.x;
  const int b0 = bh * 16 + __builtin_amdgcn_readfirstlane(t >> 6) * 4;
  const int h = ht * 64 + (t & 63);
  float acc[4] = {0,0,0,0};
  const float* wlp = Wl + c * HDIM + h;
  for (int k4 = 0; k4 < 256; ++k4) {
    float wv0 = wlp[(size_t)(k4 * 4 + 0) * NCH];
    float wv1 = wlp[(size_t)(k4 * 4 + 1) * NCH];
    float wv2 = wlp[(size_t)(k4 * 4 + 2) * NCH];
    float wv3 = wlp[(size_t)(k4 * 4 + 3) * NCH];
    #pragma unroll
    for (int bi = 0; bi < 4; ++bi) {
      float4 u = *(const float4*)&U[(size_t)((b0 + bi) * NCLS + c) * DIN + k4 * 4];
      acc[bi] += u.x * wv0 + u.y * wv1 + u.z * wv2 + u.w * wv3;
    }
  }
  float bias = bl[c * HDIM + h];
  #pragma unroll
  for (int bi = 0; bi < 4; ++bi)
    wsh[(size_t)((b0 + bi) * NCLS + c) * HDIM + h] = acc[bi] + bias;
}

// ---------------------------------------------------------------------------
// kH: hid = relu(ws@Wh+bh); bbox = hid@Wr+br; presence = hid@Wc+bc.
// grid (32 b, 12 cg3) x 256 (thread = j). ws reads uniform -> s_load.
__global__ __launch_bounds__(256) void kH_heads(
    const float* __restrict__ Wh, const float* __restrict__ bh,
    const float* __restrict__ Wr, const float* __restrict__ br,
    const float* __restrict__ Wc, const float* __restrict__ bc,
    const float* __restrict__ wsh, float* __restrict__ out) {
  __shared__ float hid_s[3][HDIM];
  const int b = blockIdx.x, c0 = blockIdx.y * 3;
  const int j = threadIdx.x;
  float acc[3] = {0,0,0};
  const float* wp = wsh + (size_t)(b * NCLS + c0) * HDIM;
  for (int h = 0; h < HDIM; ++h) {
    float whj = Wh[(size_t)h * HDIM + j];
    acc[0] += wp[h] * whj;
    acc[1] += wp[HDIM + h] * whj;
    acc[2] += wp[2 * HDIM + h] * whj;
  }
  float bj = bh[j];
  #pragma unroll
  for (int ci = 0; ci < 3; ++ci) hid_s[ci][j] = fmaxf(acc[ci] + bj, 0.0f);
  __syncthreads();
  const int r = j >> 6, j0 = j & 63;
  for (int ci = 0; ci < 3; ++ci) {
    const int c = c0 + ci;
    float s = 0.f;
    #pragma unroll
    for (int m = 0; m < 4; ++m)
      s += hid_s[ci][j0 + 64 * m] * Wr[(j0 + 64 * m) * 4 + r];
    #pragma unroll
    for (int off = 32; off >= 1; off >>= 1) s += __shfl_xor(s, off);
    if (j0 == 0) out[(size_t)b * (NCLS * 4) + c * 4 + r] = s + br[r];
    if (r == 0) {
      float p = 0.f;
      #pragma unroll
      for (int m = 0; m < 4; ++m)
        p += hid_s[ci][j0 + 64 * m] * Wc[j0 + 64 * m];
      #pragma unroll
      for (int off = 32; off >= 1; off >>= 1) p += __shfl_xor(p, off);
      if (j0 == 0) out[BSZ * NCLS * 4 + b * NCLS + c] = p + bc[0];
    }
  }
}

// ---------------------------------------------------------------------------
extern "C" void kernel_launch(void* const* d_in, const int* in_sizes, int n_in,
                              void* d_out, int out_size, void* d_ws, size_t ws_size,
                              hipStream_t stream) {
  const float* local = (const float*)d_in[0];
  const float* gap   = (const float*)d_in[1];
  const float* Wl    = (const float*)d_in[2];
  const float* bl    = (const float*)d_in[3];
  const float* Wg    = (const float*)d_in[4];
  const float* bg    = (const float*)d_in[5];
  const float* Wh    = (const float*)d_in[6];
  const float* bh    = (const float*)d_in[7];
  const float* Wr    = (const float*)d_in[8];
  const float* br    = (const float*)d_in[9];
  const float* Wc    = (const float*)d_in[10];
  const float* bc    = (const float*)d_in[11];
  float* out         = (float*)d_out;

  float* ws      = (float*)d_ws;
  float* xg_part = ws;                    // 4*XG_N
  float* xg      = xg_part + 4 * XG_N;    // XG_N
  float* V       = xg + XG_N;             // V_N
  float* sc_part = V + V_N;               // 4*SC_N
  float* attn_t  = sc_part + 4 * (size_t)SC_N; // SC_N
  float* U       = attn_t + SC_N;         // V_N
  float* wsh     = U + V_N;               // XG_N
  // total 5,257,728 floats = 21.0 MB

  kB_xg_part<<<dim3(72, 4), dim3(256), 0, stream>>>(Wg, gap, xg_part);
  kBr_xg<<<dim3(XG_N / 256), dim3(256), 0, stream>>>(xg_part, bg, xg);
  kC_V<<<dim3(36, 8), dim3(256), 0, stream>>>(Wl, xg, V);
  kD_scores<<<dim3(32, 3, 4), dim3(256), 0, stream>>>(local, V, sc_part);
  kE_softmax<<<dim3(32, 36), dim3(64), 0, stream>>>(sc_part, attn_t);
  kF_U<<<dim3(32, 4, 3), dim3(256), 0, stream>>>(local, attn_t, U);
  kG_ws<<<dim3(36, 4, 2), dim3(256), 0, stream>>>(Wl, U, bl, wsh);
  kH_heads<<<dim3(32, 12), dim3(256), 0, stream>>>(Wh, bh, Wr, br, Wc, bc, wsh, out);
}

// Round 4
// 284.651 us; speedup vs baseline: 2.3407x; 1.1619x over previous
//
#include <hip/hip_runtime.h>
#include <hip/hip_bf16.h>
#include <stdint.h>

#define NCLS 36
#define HDIM 256
#define BSZ  32
#define LLOC 196
#define DIN  1024
#define NCH  9216          // NCLS*HDIM

#define XG_N 294912        // BSZ*NCH
#define SC_N 225792        // BSZ*NCLS*LLOC
#define V_N  1179648       // BSZ*NCLS*DIN

// ---------------------------------------------------------------------------
// kB: xg_part[ks][b][n] = sum_{k in chunk} gap[b][k] * Wg[k][n]
// grid (36 ntile256, 8 ksplit, 2 bg16) x 256. thread = n (coalesced Wg),
// gap reads are block-uniform -> scalar loads.
__global__ __launch_bounds__(256) void kB_xg_part(
    const float* __restrict__ Wg, const float* __restrict__ gap,
    float* __restrict__ xg_part) {
  const int n  = blockIdx.x * 256 + threadIdx.x;
  const int kc = blockIdx.y * 128;
  const int b0 = blockIdx.z * 16;
  float acc[16] = {0,0,0,0,0,0,0,0,0,0,0,0,0,0,0,0};
  const float* wp = Wg + (size_t)kc * NCH + n;
  const float* gp = gap + (size_t)b0 * DIN + kc;
  for (int k4 = 0; k4 < 32; ++k4) {
    float w0 = wp[(size_t)(k4 * 4 + 0) * NCH];
    float w1 = wp[(size_t)(k4 * 4 + 1) * NCH];
    float w2 = wp[(size_t)(k4 * 4 + 2) * NCH];
    float w3 = wp[(size_t)(k4 * 4 + 3) * NCH];
    #pragma unroll
    for (int bi = 0; bi < 16; ++bi) {
      float4 g = *(const float4*)&gp[(size_t)bi * DIN + k4 * 4];  // uniform -> s_load
      acc[bi] += g.x * w0 + g.y * w1 + g.z * w2 + g.w * w3;
    }
  }
  #pragma unroll
  for (int bi = 0; bi < 16; ++bi)
    xg_part[(size_t)blockIdx.y * XG_N + (size_t)(b0 + bi) * NCH + n] = acc[bi];
}

// kBr: xg = bg + sum of 8 partials. grid 1152 x 256.
__global__ void kBr_xg(const float* __restrict__ xg_part,
                       const float* __restrict__ bg, float* __restrict__ xg) {
  int i = blockIdx.x * 256 + threadIdx.x;
  float s = bg[i % NCH];
  #pragma unroll
  for (int p = 0; p < 8; ++p) s += xg_part[(size_t)p * XG_N + i];
  xg[i] = s;
}

// ---------------------------------------------------------------------------
// kC: V[b][c][k] = sum_h Wl[k][c*256+h] * xg[b][c*256+h]
// grid (36 c, 4 kc256, 2 bg16) x 256. thread = k (per-lane row walk of Wl,
// lines amortized in L1); xg reads block-uniform -> scalar loads.
__global__ __launch_bounds__(256) void kC_V(
    const float* __restrict__ Wl, const float* __restrict__ xg,
    float* __restrict__ V) {
  const int c  = blockIdx.x;
  const int k  = blockIdx.y * 256 + threadIdx.x;
  const int b0 = blockIdx.z * 16;
  float acc[16] = {0,0,0,0,0,0,0,0,0,0,0,0,0,0,0,0};
  const float* wl = Wl + (size_t)k * NCH + c * HDIM;
  const float* xp = xg + (size_t)b0 * NCH + c * HDIM;
  for (int j = 0; j < 64; ++j) {
    float4 w = *(const float4*)&wl[j * 4];
    #pragma unroll
    for (int bi = 0; bi < 16; ++bi) {
      float4 x = *(const float4*)&xp[(size_t)bi * NCH + j * 4];   // uniform -> s_load
      acc[bi] += w.x * x.x + w.y * x.y + w.z * x.z + w.w * x.w;
    }
  }
  #pragma unroll
  for (int bi = 0; bi < 16; ++bi)
    V[(size_t)((b0 + bi) * NCLS + c) * DIN + k] = acc[bi];
}

// ---------------------------------------------------------------------------
// kD: sc_part[ks][b][c][l] = sum_{k chunk128} local[b][l][k] * V[b][c][k]
// grid (32 b, 3 cg12, 8 ks) x 256 (196 active, thread = l). V -> scalar loads.
__global__ __launch_bounds__(256) void kD_scores(
    const float* __restrict__ local, const float* __restrict__ V,
    float* __restrict__ sc_part) {
  const int b  = blockIdx.x;
  const int cg = blockIdx.y;
  const int ks = blockIdx.z;
  const int l  = threadIdx.x;
  if (l >= LLOC) return;
  const float* lp = local + (size_t)(b * LLOC + l) * DIN + ks * 128;
  const float* vp = V + (size_t)(b * NCLS + cg * 12) * DIN + ks * 128;
  float acc[12] = {0,0,0,0,0,0,0,0,0,0,0,0};
  for (int j = 0; j < 32; ++j) {
    float4 a = *(const float4*)&lp[j * 4];
    #pragma unroll
    for (int ci = 0; ci < 12; ++ci) {
      float4 v = *(const float4*)&vp[(size_t)ci * DIN + j * 4];   // uniform -> s_load
      acc[ci] += a.x * v.x + a.y * v.y + a.z * v.z + a.w * v.w;
    }
  }
  #pragma unroll
  for (int ci = 0; ci < 12; ++ci)
    sc_part[(size_t)ks * SC_N + (size_t)(b * NCLS + cg * 12 + ci) * LLOC + l] = acc[ci];
}

// ---------------------------------------------------------------------------
// kE: sum 8 partials + softmax over l; write attn2[b][c][l] (coalesced).
// grid (32, 36) x 64.
__global__ __launch_bounds__(64) void kE_softmax(
    const float* __restrict__ sc_part, float* __restrict__ attn2) {
  const int b = blockIdx.x, c = blockIdx.y, t = threadIdx.x;
  const size_t base = (size_t)(b * NCLS + c) * LLOC;
  float sc[4];
  int nl = 0;
  float m = -1e30f;
  for (int l = t; l < LLOC; l += 64) {
    float s = 0.f;
    #pragma unroll
    for (int p = 0; p < 8; ++p) s += sc_part[(size_t)p * SC_N + base + l];
    sc[nl++] = s; m = fmaxf(m, s);
  }
  #pragma unroll
  for (int off = 32; off >= 1; off >>= 1) m = fmaxf(m, __shfl_xor(m, off));
  float sum = 0.f;
  for (int i = 0; i < nl; ++i) { sc[i] = __expf(sc[i] - m); sum += sc[i]; }
  #pragma unroll
  for (int off = 32; off >= 1; off >>= 1) sum += __shfl_xor(sum, off);
  float inv = 1.0f / sum;
  nl = 0;
  for (int l = t; l < LLOC; l += 64) attn2[base + l] = sc[nl++] * inv;
}

// ---------------------------------------------------------------------------
// kF: U[b][c][k] = sum_l attn2[b][c][l] * local[b][l][k]
// grid (32 b, 4 ks256, 3 cg12) x 256 (thread = k, coalesced local).
// attn2 reads block-uniform -> scalar loads (dwordx4 over l).
__global__ __launch_bounds__(256) void kF_U(
    const float* __restrict__ local, const float* __restrict__ attn2,
    float* __restrict__ U) {
  const int b = blockIdx.x, cg = blockIdx.z;
  const int k = blockIdx.y * 256 + threadIdx.x;
  float acc[12] = {0,0,0,0,0,0,0,0,0,0,0,0};
  const float* lp = local + (size_t)b * LLOC * DIN + k;
  const float* ap = attn2 + (size_t)(b * NCLS + cg * 12) * LLOC;
  for (int l4 = 0; l4 < 49; ++l4) {
    float a0 = lp[(size_t)(l4 * 4 + 0) * DIN];
    float a1 = lp[(size_t)(l4 * 4 + 1) * DIN];
    float a2 = lp[(size_t)(l4 * 4 + 2) * DIN];
    float a3 = lp[(size_t)(l4 * 4 + 3) * DIN];
    #pragma unroll
    for (int ci = 0; ci < 12; ++ci) {
      float4 w = *(const float4*)&ap[(size_t)ci * LLOC + l4 * 4];  // uniform -> s_load
      acc[ci] += a0 * w.x + a1 * w.y + a2 * w.z + a3 * w.w;
    }
  }
  #pragma unroll
  for (int ci = 0; ci < 12; ++ci)
    U[(size_t)(b * NCLS + cg * 12 + ci) * DIN + k] = acc[ci];
}

// ---------------------------------------------------------------------------
// kG: wsh_part[ks][b][c][h] = sum_{k chunk128} U[b][c][k] * Wl[k][c*256+h]
// grid (36 c, 8 ks, 2 bg16) x 256. thread = h (coalesced Wl), U -> scalar loads.
__global__ __launch_bounds__(256) void kG_ws(
    const float* __restrict__ Wl, const float* __restrict__ U,
    float* __restrict__ wsh_part) {
  const int c  = blockIdx.x;
  const int kc = blockIdx.y * 128;
  const int b0 = blockIdx.z * 16;
  const int h  = threadIdx.x;
  float acc[16] = {0,0,0,0,0,0,0,0,0,0,0,0,0,0,0,0};
  const float* wp = Wl + (size_t)kc * NCH + c * HDIM + h;
  const float* up = U + (size_t)(b0 * NCLS + c) * DIN + kc;
  for (int k4 = 0; k4 < 32; ++k4) {
    float w0 = wp[(size_t)(k4 * 4 + 0) * NCH];
    float w1 = wp[(size_t)(k4 * 4 + 1) * NCH];
    float w2 = wp[(size_t)(k4 * 4 + 2) * NCH];
    float w3 = wp[(size_t)(k4 * 4 + 3) * NCH];
    #pragma unroll
    for (int bi = 0; bi < 16; ++bi) {
      float4 u = *(const float4*)&up[(size_t)bi * NCLS * DIN + k4 * 4]; // uniform -> s_load
      acc[bi] += u.x * w0 + u.y * w1 + u.z * w2 + u.w * w3;
    }
  }
  #pragma unroll
  for (int bi = 0; bi < 16; ++bi)
    wsh_part[(size_t)blockIdx.y * XG_N + (size_t)(b0 + bi) * NCH + c * HDIM + h] = acc[bi];
}

// ---------------------------------------------------------------------------
// kH: ws = sum8 wsh_part + bl; hid = relu(ws@Wh+bh); bbox/presence heads.
// grid (32 b, 12 cg3) x 256 (thread = j).
__global__ __launch_bounds__(256) void kH_heads(
    const float* __restrict__ Wh, const float* __restrict__ bh,
    const float* __restrict__ Wr, const float* __restrict__ br,
    const float* __restrict__ Wc, const float* __restrict__ bc,
    const float* __restrict__ bl,
    const float* __restrict__ wsh_part, float* __restrict__ out) {
  __shared__ float ws_s[3][HDIM];
  __shared__ float hid_s[3][HDIM];
  const int b = blockIdx.x, c0 = blockIdx.y * 3;
  const int j = threadIdx.x;

  #pragma unroll
  for (int ci = 0; ci < 3; ++ci) {
    size_t base = (size_t)b * NCH + (c0 + ci) * HDIM + j;
    float s = bl[(c0 + ci) * HDIM + j];
    #pragma unroll
    for (int p = 0; p < 8; ++p) s += wsh_part[(size_t)p * XG_N + base];
    ws_s[ci][j] = s;
  }
  __syncthreads();

  float acc[3] = {0,0,0};
  for (int h = 0; h < HDIM; ++h) {
    float whj = Wh[(size_t)h * HDIM + j];
    acc[0] += ws_s[0][h] * whj;
    acc[1] += ws_s[1][h] * whj;
    acc[2] += ws_s[2][h] * whj;
  }
  float bj = bh[j];
  #pragma unroll
  for (int ci = 0; ci < 3; ++ci) hid_s[ci][j] = fmaxf(acc[ci] + bj, 0.0f);
  __syncthreads();

  const int r = j >> 6, j0 = j & 63;
  for (int ci = 0; ci < 3; ++ci) {
    const int c = c0 + ci;
    float s = 0.f;
    #pragma unroll
    for (int m = 0; m < 4; ++m)
      s += hid_s[ci][j0 + 64 * m] * Wr[(j0 + 64 * m) * 4 + r];
    #pragma unroll
    for (int off = 32; off >= 1; off >>= 1) s += __shfl_xor(s, off);
    if (j0 == 0) out[(size_t)b * (NCLS * 4) + c * 4 + r] = s + br[r];
    if (r == 0) {
      float p = 0.f;
      #pragma unroll
      for (int m = 0; m < 4; ++m)
        p += hid_s[ci][j0 + 64 * m] * Wc[j0 + 64 * m];
      #pragma unroll
      for (int off = 32; off >= 1; off >>= 1) p += __shfl_xor(p, off);
      if (j0 == 0) out[BSZ * NCLS * 4 + b * NCLS + c] = p + bc[0];
    }
  }
}

// ---------------------------------------------------------------------------
extern "C" void kernel_launch(void* const* d_in, const int* in_sizes, int n_in,
                              void* d_out, int out_size, void* d_ws, size_t ws_size,
                              hipStream_t stream) {
  const float* local = (const float*)d_in[0];
  const float* gap   = (const float*)d_in[1];
  const float* Wl    = (const float*)d_in[2];
  const float* bl    = (const float*)d_in[3];
  const float* Wg    = (const float*)d_in[4];
  const float* bg    = (const float*)d_in[5];
  const float* Wh    = (const float*)d_in[6];
  const float* bh    = (const float*)d_in[7];
  const float* Wr    = (const float*)d_in[8];
  const float* br    = (const float*)d_in[9];
  const float* Wc    = (const float*)d_in[10];
  const float* bc    = (const float*)d_in[11];
  float* out         = (float*)d_out;

  // Workspace layout with reuse (total ~21 MB):
  // A: 8*XG_N floats — xg_part, then sc_part (8*SC_N fits), then wsh_part
  // B: XG_N — xg;  C: V_N — V;  D: SC_N — attn2;  E: V_N — U
  float* A  = (float*)d_ws;
  float* B  = A + (size_t)8 * XG_N;
  float* C  = B + XG_N;
  float* D  = C + V_N;
  float* E  = D + SC_N;

  kB_xg_part<<<dim3(36, 8, 2), dim3(256), 0, stream>>>(Wg, gap, A);
  kBr_xg<<<dim3(XG_N / 256), dim3(256), 0, stream>>>(A, bg, B);
  kC_V<<<dim3(36, 4, 2), dim3(256), 0, stream>>>(Wl, B, C);
  kD_scores<<<dim3(32, 3, 8), dim3(256), 0, stream>>>(local, C, A);
  kE_softmax<<<dim3(32, 36), dim3(64), 0, stream>>>(A, D);
  kF_U<<<dim3(32, 4, 3), dim3(256), 0, stream>>>(local, D, E);
  kG_ws<<<dim3(36, 8, 2), dim3(256), 0, stream>>>(Wl, E, A);
  kH_heads<<<dim3(32, 12), dim3(256), 0, stream>>>(Wh, bh, Wr, br, Wc, bc, bl, A, out);
}